// Round 3
// baseline (1357.268 us; speedup 1.0000x reference)
//
#include <hip/hip_runtime.h>

#define N_NODES 500000
#define N_EDGES 8000000
#define W_BKT 512
#define LOG_W 9
#define NBKT ((N_NODES + W_BKT - 1) / W_BKT)   // 977
#define SRC_MASK 0x7FFFFu                       // 19 bits
#define P1_BLK 256
#define P1_EPT 128
#define P1_CHUNK (P1_BLK * P1_EPT)              // 32768 edges per block
#define P1_BLOCKS ((N_EDGES + P1_CHUNK - 1) / P1_CHUNK)  // 245

typedef unsigned int uint;

__device__ __forceinline__ float leaky_f(float x) { return x > 0.0f ? x : 0.1f * x; }

// ---------------------------------------------------------------------------
// FAST PATH
// ---------------------------------------------------------------------------

__global__ void k0_zero(uint* __restrict__ counts) {
    int t = blockIdx.x * blockDim.x + threadIdx.x;
    if (t < 3 * NBKT) counts[t] = 0;
}

// k1: X4[s][i] = (x@W_s)[i][0..3], X12[s][i] = {(x@W_s)[i][4], 0}
__global__ void k1_hx(const float* __restrict__ x,
                      const float* __restrict__ Wp,
                      const float* __restrict__ Ws,
                      const float* __restrict__ Wv,
                      float4* __restrict__ X4,
                      float2* __restrict__ X12)
{
    __shared__ float sW[3][25][5];
    int t = threadIdx.x;
    if (t < 125) {
        sW[0][t / 5][t % 5] = Wp[t];
        sW[1][t / 5][t % 5] = Ws[t];
        sW[2][t / 5][t % 5] = Wv[t];
    }
    __syncthreads();
    int i = blockIdx.x * blockDim.x + t;
    if (i >= N_NODES) return;
    float xi[25];
#pragma unroll
    for (int k = 0; k < 25; ++k) xi[k] = x[i * 25 + k];
#pragma unroll
    for (int s = 0; s < 3; ++s) {
        float acc[5] = {0.f, 0.f, 0.f, 0.f, 0.f};
#pragma unroll
        for (int k = 0; k < 25; ++k)
#pragma unroll
            for (int c = 0; c < 5; ++c) acc[c] = fmaf(xi[k], sW[s][k][c], acc[c]);
        size_t idx = (size_t)s * N_NODES + i;
        X4[idx] = make_float4(acc[0], acc[1], acc[2], acc[3]);
        X12[idx] = make_float2(acc[4], 0.f);
    }
}

// P1a: per-bucket edge counts
__global__ void p1_count(const int* __restrict__ ep,
                         const int* __restrict__ es,
                         const int* __restrict__ ev,
                         uint* __restrict__ counts)
{
    int s = blockIdx.y;
    const int* ei = (s == 0) ? ep : ((s == 1) ? es : ev);
    const int* dstp = ei + N_EDGES;
    __shared__ uint hist[NBKT];
    for (int b = threadIdx.x; b < NBKT; b += P1_BLK) hist[b] = 0;
    __syncthreads();
    int start = blockIdx.x * P1_CHUNK;
#pragma unroll 4
    for (int j = 0; j < P1_EPT; ++j) {
        int idx = start + j * P1_BLK + threadIdx.x;
        if (idx < N_EDGES) atomicAdd(&hist[((uint)dstp[idx]) >> LOG_W], 1u);
    }
    __syncthreads();
    for (int b = threadIdx.x; b < NBKT; b += P1_BLK)
        if (hist[b]) atomicAdd(&counts[s * NBKT + b], hist[b]);
}

// P1b: parallel exclusive scan per set (one block per set, Hillis-Steele in LDS)
__global__ void p1_scan(const uint* __restrict__ counts,
                        uint* __restrict__ base,
                        uint* __restrict__ cursor)
{
    __shared__ uint buf[1024];
    int s = blockIdx.x;
    int t = threadIdx.x;
    uint v = (t < NBKT) ? counts[s * NBKT + t] : 0u;
    buf[t] = v;
    __syncthreads();
    for (int off = 1; off < 1024; off <<= 1) {
        uint add = (t >= off) ? buf[t - off] : 0u;
        __syncthreads();
        buf[t] += add;
        __syncthreads();
    }
    if (t < NBKT) {
        uint ex = buf[t] - v;
        base[s * NBKT + t] = ex;
        cursor[s * NBKT + t] = ex;
    }
}

// P1c: scatter edges into bucket-sorted array, packed (local_dst<<19 | src)
__global__ void p1_scatter(const int* __restrict__ ep,
                           const int* __restrict__ es,
                           const int* __restrict__ ev,
                           uint* __restrict__ cursor,
                           uint* __restrict__ parts)
{
    int s = blockIdx.y;
    const int* ei = (s == 0) ? ep : ((s == 1) ? es : ev);
    const int* srcp = ei;
    const int* dstp = ei + N_EDGES;
    uint* part = parts + (size_t)s * N_EDGES;
    __shared__ uint hist[NBKT];
    __shared__ uint bbase[NBKT];
    for (int b = threadIdx.x; b < NBKT; b += P1_BLK) hist[b] = 0;
    __syncthreads();
    int start = blockIdx.x * P1_CHUNK;
#pragma unroll 4
    for (int j = 0; j < P1_EPT; ++j) {
        int idx = start + j * P1_BLK + threadIdx.x;
        if (idx < N_EDGES) atomicAdd(&hist[((uint)dstp[idx]) >> LOG_W], 1u);
    }
    __syncthreads();
    for (int b = threadIdx.x; b < NBKT; b += P1_BLK) {
        uint c = hist[b];
        if (c) bbase[b] = atomicAdd(&cursor[s * NBKT + b], c);
        hist[b] = 0;
    }
    __syncthreads();
#pragma unroll 4
    for (int j = 0; j < P1_EPT; ++j) {
        int idx = start + j * P1_BLK + threadIdx.x;
        if (idx < N_EDGES) {
            uint dst = (uint)dstp[idx];
            uint b = dst >> LOG_W;
            uint r = atomicAdd(&hist[b], 1u);
            part[bbase[b] + r] = ((dst & (W_BKT - 1u)) << 19) | (uint)srcp[idx];
        }
    }
}

// P2a: per-bucket degree via LDS hist, then premultiply:
//      X4[i] *= rsqrt(deg), X12[i] = {h4*rsqrt(deg), rsqrt(deg)}
__global__ void p2_prep(const uint* __restrict__ parts,
                        const uint* __restrict__ base,
                        const uint* __restrict__ counts,
                        float4* __restrict__ X4,
                        float2* __restrict__ X12)
{
    int b = blockIdx.x;
    __shared__ uint cnt[3 * W_BKT];
    for (int t = threadIdx.x; t < 3 * W_BKT; t += blockDim.x) cnt[t] = 0;
    __syncthreads();
    for (int s = 0; s < 3; ++s) {
        uint s0 = base[s * NBKT + b], c0 = counts[s * NBKT + b];
        const uint* part = parts + (size_t)s * N_EDGES + s0;
        for (uint i = threadIdx.x; i < c0; i += blockDim.x)
            atomicAdd(&cnt[(s << LOG_W) + (part[i] >> 19)], 1u);
    }
    __syncthreads();
    int nb = b << LOG_W;
    for (int t = threadIdx.x; t < 3 * W_BKT; t += blockDim.x) {
        int s = t >> LOG_W;
        int n = t & (W_BKT - 1);
        int node = nb + n;
        if (node < N_NODES) {
            float rd = rsqrtf(1.0f + (float)cnt[t]);
            size_t idx = (size_t)s * N_NODES + node;
            float4 v = X4[idx];
            v.x *= rd; v.y *= rd; v.z *= rd; v.w *= rd;
            X4[idx] = v;
            float2 w = X12[idx];
            X12[idx] = make_float2(w.x * rd, rd);
        }
    }
}

// P2b: per-bucket aggregate in LDS + fused MLP. 4-edge ILP in the gather loop.
__global__ __launch_bounds__(256) void p2_agg(
    const uint* __restrict__ parts, const uint* __restrict__ base,
    const uint* __restrict__ counts,
    const float4* __restrict__ X4, const float2* __restrict__ X12,
    const float* __restrict__ bp, const float* __restrict__ bs, const float* __restrict__ bv,
    const float* __restrict__ pw1, const float* __restrict__ pb1,
    const float* __restrict__ pw2, const float* __restrict__ pb2,
    const float* __restrict__ cw1, const float* __restrict__ cb1,
    const float* __restrict__ cw2, const float* __restrict__ cb2,
    float* __restrict__ out)
{
    __shared__ float acc[3 * W_BKT * 5];   // 30720 B
    __shared__ float rdd[3 * W_BKT];       // 6144 B
    __shared__ float wts[272];
    int tid = threadIdx.x;
    for (int j = tid; j < 272; j += blockDim.x) {
        float v;
        if (j < 150) v = pw1[j];
        else if (j < 160) v = pb1[j - 150];
        else if (j < 210) v = pw2[j - 160];
        else if (j < 215) v = pb2[j - 210];
        else if (j < 240) v = cw1[j - 215];
        else if (j < 245) v = cb1[j - 240];
        else if (j < 255) v = cw2[j - 245];
        else if (j < 257) v = cb2[j - 255];
        else if (j < 262) v = bp[j - 257];
        else if (j < 267) v = bs[j - 262];
        else v = bv[j - 267];
        wts[j] = v;
    }
    int b = blockIdx.x;
    int nb = b << LOG_W;
    __syncthreads();

    // stage rsqrt(deg_dst) + self-loop/bias init:  acc = (h*rd)*rd + bias
    for (int t = tid; t < 3 * W_BKT; t += blockDim.x) {
        int s = t >> LOG_W;
        int n = t & (W_BKT - 1);
        int node = nb + n;
        float* a = &acc[t * 5];
        if (node < N_NODES) {
            size_t idx = (size_t)s * N_NODES + node;
            float4 v = X4[idx];
            float2 w = X12[idx];
            float rd = w.y;
            rdd[t] = rd;
            const float* bb = &wts[257 + s * 5];
            a[0] = fmaf(v.x, rd, bb[0]);
            a[1] = fmaf(v.y, rd, bb[1]);
            a[2] = fmaf(v.z, rd, bb[2]);
            a[3] = fmaf(v.w, rd, bb[3]);
            a[4] = fmaf(w.x, rd, bb[4]);
        } else {
            rdd[t] = 0.f;
#pragma unroll
            for (int c = 0; c < 5; ++c) a[c] = 0.f;
        }
    }
    __syncthreads();

    // edge aggregation into LDS, 4-edge ILP
    for (int s = 0; s < 3; ++s) {
        uint s0 = base[s * NBKT + b], c0 = counts[s * NBKT + b];
        const uint* part = parts + (size_t)s * N_EDGES + s0;
        const float4* X4s = X4 + (size_t)s * N_NODES;
        const float2* X12s = X12 + (size_t)s * N_NODES;
        float* accs = acc + s * (W_BKT * 5);
        const float* rs = rdd + (s << LOG_W);

        const uint per = 4u * 256u;
        uint nfull = (c0 / per) * per;
        for (uint i0 = 4u * tid; i0 < nfull; i0 += per) {
            uint k0 = part[i0], k1 = part[i0 + 1], k2 = part[i0 + 2], k3 = part[i0 + 3];
            float4 a0 = X4s[k0 & SRC_MASK];
            float4 a1 = X4s[k1 & SRC_MASK];
            float4 a2 = X4s[k2 & SRC_MASK];
            float4 a3 = X4s[k3 & SRC_MASK];
            float e0 = X12s[k0 & SRC_MASK].x;
            float e1 = X12s[k1 & SRC_MASK].x;
            float e2 = X12s[k2 & SRC_MASK].x;
            float e3 = X12s[k3 & SRC_MASK].x;
            float r0 = rs[k0 >> 19], r1 = rs[k1 >> 19], r2 = rs[k2 >> 19], r3 = rs[k3 >> 19];
            {
                float* A = &accs[(k0 >> 19) * 5];
                atomicAdd(A + 0, a0.x * r0); atomicAdd(A + 1, a0.y * r0);
                atomicAdd(A + 2, a0.z * r0); atomicAdd(A + 3, a0.w * r0);
                atomicAdd(A + 4, e0 * r0);
            }
            {
                float* A = &accs[(k1 >> 19) * 5];
                atomicAdd(A + 0, a1.x * r1); atomicAdd(A + 1, a1.y * r1);
                atomicAdd(A + 2, a1.z * r1); atomicAdd(A + 3, a1.w * r1);
                atomicAdd(A + 4, e1 * r1);
            }
            {
                float* A = &accs[(k2 >> 19) * 5];
                atomicAdd(A + 0, a2.x * r2); atomicAdd(A + 1, a2.y * r2);
                atomicAdd(A + 2, a2.z * r2); atomicAdd(A + 3, a2.w * r2);
                atomicAdd(A + 4, e2 * r2);
            }
            {
                float* A = &accs[(k3 >> 19) * 5];
                atomicAdd(A + 0, a3.x * r3); atomicAdd(A + 1, a3.y * r3);
                atomicAdd(A + 2, a3.z * r3); atomicAdd(A + 3, a3.w * r3);
                atomicAdd(A + 4, e3 * r3);
            }
        }
        for (uint i = nfull + tid; i < c0; i += 256u) {
            uint k = part[i];
            uint src = k & SRC_MASK;
            uint ld = k >> 19;
            float4 a0 = X4s[src];
            float e0 = X12s[src].x;
            float r = rs[ld];
            float* A = &accs[ld * 5];
            atomicAdd(A + 0, a0.x * r); atomicAdd(A + 1, a0.y * r);
            atomicAdd(A + 2, a0.z * r); atomicAdd(A + 3, a0.w * r);
            atomicAdd(A + 4, e0 * r);
        }
    }
    __syncthreads();

    // fused MLP epilogue
    const float* W1 = wts;          // [15][10]
    const float* B1 = wts + 150;
    const float* W2 = wts + 160;    // [10][5]
    const float* B2 = wts + 210;
    const float* C1 = wts + 215;    // [5][5]
    const float* D1 = wts + 240;
    const float* C2 = wts + 245;    // [5][2]
    const float* D2 = wts + 255;
    for (int n = tid; n < W_BKT; n += blockDim.x) {
        int node = nb + n;
        if (node >= N_NODES) break;
        float hin[15];
#pragma unroll
        for (int s = 0; s < 3; ++s)
#pragma unroll
            for (int c = 0; c < 5; ++c)
                hin[s * 5 + c] = leaky_f(acc[(s * W_BKT + n) * 5 + c]);
        float h1[10];
#pragma unroll
        for (int o = 0; o < 10; ++o) h1[o] = B1[o];
#pragma unroll
        for (int k = 0; k < 15; ++k)
#pragma unroll
            for (int o = 0; o < 10; ++o) h1[o] = fmaf(hin[k], W1[k * 10 + o], h1[o]);
#pragma unroll
        for (int o = 0; o < 10; ++o) h1[o] = leaky_f(h1[o]);
        float h2[5];
#pragma unroll
        for (int o = 0; o < 5; ++o) h2[o] = B2[o];
#pragma unroll
        for (int k = 0; k < 10; ++k)
#pragma unroll
            for (int o = 0; o < 5; ++o) h2[o] = fmaf(h1[k], W2[k * 5 + o], h2[o]);
        float h3[5];
#pragma unroll
        for (int o = 0; o < 5; ++o) h3[o] = D1[o];
#pragma unroll
        for (int k = 0; k < 5; ++k)
#pragma unroll
            for (int o = 0; o < 5; ++o) h3[o] = fmaf(h2[k], C1[k * 5 + o], h3[o]);
#pragma unroll
        for (int o = 0; o < 5; ++o) h3[o] = leaky_f(h3[o]);
        float o0 = D2[0], o1 = D2[1];
#pragma unroll
        for (int k = 0; k < 5; ++k) {
            o0 = fmaf(h3[k], C2[k * 2 + 0], o0);
            o1 = fmaf(h3[k], C2[k * 2 + 1], o1);
        }
        out[(size_t)node * 2 + 0] = o0;
        out[(size_t)node * 2 + 1] = o1;
    }
}

// ---------------------------------------------------------------------------
// FALLBACK PATH (round-0 pipeline, used only if ws too small)
// ---------------------------------------------------------------------------

__global__ void k1_gemm_deginit(const float* __restrict__ x,
                                const float* __restrict__ Wp,
                                const float* __restrict__ Ws,
                                const float* __restrict__ Wv,
                                float* __restrict__ h, float* __restrict__ deg)
{
    __shared__ float sW[3][25][5];
    int t = threadIdx.x;
    if (t < 125) { sW[0][t/5][t%5]=Wp[t]; sW[1][t/5][t%5]=Ws[t]; sW[2][t/5][t%5]=Wv[t]; }
    __syncthreads();
    for (int i = blockIdx.x * blockDim.x + t; i < N_NODES; i += gridDim.x * blockDim.x) {
        float xi[25];
#pragma unroll
        for (int k = 0; k < 25; ++k) xi[k] = x[i * 25 + k];
#pragma unroll
        for (int s = 0; s < 3; ++s) {
            float acc[5] = {0.f,0.f,0.f,0.f,0.f};
#pragma unroll
            for (int k = 0; k < 25; ++k)
#pragma unroll
                for (int c = 0; c < 5; ++c) acc[c] = fmaf(xi[k], sW[s][k][c], acc[c]);
#pragma unroll
            for (int c = 0; c < 5; ++c) h[(s * N_NODES + i) * 5 + c] = acc[c];
            deg[s * N_NODES + i] = 1.0f;
        }
    }
}

__global__ void k2_degree(const int* __restrict__ ep, const int* __restrict__ es,
                          const int* __restrict__ ev, float* __restrict__ deg)
{
    long e = (long)blockIdx.x * blockDim.x + threadIdx.x;
    if (e >= 3L * N_EDGES) return;
    int s = (int)(e / N_EDGES);
    int i = (int)(e - (long)s * N_EDGES);
    const int* ei = (s == 0) ? ep : ((s == 1) ? es : ev);
    atomicAdd(&deg[s * N_NODES + ei[N_EDGES + i]], 1.0f);
}

__global__ void k3_accum_init(const float* __restrict__ h, const float* __restrict__ deg,
                              const float* __restrict__ bp, const float* __restrict__ bs,
                              const float* __restrict__ bv, float* __restrict__ accum)
{
    int i = blockIdx.x * blockDim.x + threadIdx.x;
    if (i >= N_NODES) return;
#pragma unroll
    for (int s = 0; s < 3; ++s) {
        const float* b = (s == 0) ? bp : ((s == 1) ? bs : bv);
        float inv = 1.0f / deg[s * N_NODES + i];
#pragma unroll
        for (int c = 0; c < 5; ++c)
            accum[(s * N_NODES + i) * 5 + c] = h[(s * N_NODES + i) * 5 + c] * inv + b[c];
    }
}

__global__ void k4_scatter(const int* __restrict__ ep, const int* __restrict__ es,
                           const int* __restrict__ ev, const float* __restrict__ h,
                           const float* __restrict__ deg, float* __restrict__ accum)
{
    long e = (long)blockIdx.x * blockDim.x + threadIdx.x;
    if (e >= 3L * N_EDGES) return;
    int s = (int)(e / N_EDGES);
    int i = (int)(e - (long)s * N_EDGES);
    const int* ei = (s == 0) ? ep : ((s == 1) ? es : ev);
    int src = ei[i];
    int dst = ei[N_EDGES + i];
    float norm = rsqrtf(deg[s * N_NODES + src] * deg[s * N_NODES + dst]);
    const float* hp = h + (size_t)(s * N_NODES + src) * 5;
    float* ap = accum + (size_t)(s * N_NODES + dst) * 5;
#pragma unroll
    for (int c = 0; c < 5; ++c) atomicAdd(&ap[c], hp[c] * norm);
}

__global__ void k5_mlp(const float* __restrict__ accum,
                       const float* __restrict__ pw1, const float* __restrict__ pb1,
                       const float* __restrict__ pw2, const float* __restrict__ pb2,
                       const float* __restrict__ cw1, const float* __restrict__ cb1,
                       const float* __restrict__ cw2, const float* __restrict__ cb2,
                       float* __restrict__ out)
{
    __shared__ float sw[257];
    for (int j = threadIdx.x; j < 257; j += blockDim.x) {
        float v;
        if (j < 150) v = pw1[j];
        else if (j < 160) v = pb1[j - 150];
        else if (j < 210) v = pw2[j - 160];
        else if (j < 215) v = pb2[j - 210];
        else if (j < 240) v = cw1[j - 215];
        else if (j < 245) v = cb1[j - 240];
        else if (j < 255) v = cw2[j - 245];
        else v = cb2[j - 255];
        sw[j] = v;
    }
    __syncthreads();
    const float* W1 = sw; const float* B1 = sw + 150; const float* W2 = sw + 160;
    const float* B2 = sw + 210; const float* C1 = sw + 215; const float* D1 = sw + 240;
    const float* C2 = sw + 245; const float* D2 = sw + 255;
    int i = blockIdx.x * blockDim.x + threadIdx.x;
    if (i >= N_NODES) return;
    float hin[15];
#pragma unroll
    for (int s = 0; s < 3; ++s)
#pragma unroll
        for (int c = 0; c < 5; ++c)
            hin[s * 5 + c] = leaky_f(accum[(size_t)(s * N_NODES + i) * 5 + c]);
    float h1[10];
#pragma unroll
    for (int o = 0; o < 10; ++o) h1[o] = B1[o];
#pragma unroll
    for (int k = 0; k < 15; ++k)
#pragma unroll
        for (int o = 0; o < 10; ++o) h1[o] = fmaf(hin[k], W1[k * 10 + o], h1[o]);
#pragma unroll
    for (int o = 0; o < 10; ++o) h1[o] = leaky_f(h1[o]);
    float h2[5];
#pragma unroll
    for (int o = 0; o < 5; ++o) h2[o] = B2[o];
#pragma unroll
    for (int k = 0; k < 10; ++k)
#pragma unroll
        for (int o = 0; o < 5; ++o) h2[o] = fmaf(h1[k], W2[k * 5 + o], h2[o]);
    float h3[5];
#pragma unroll
    for (int o = 0; o < 5; ++o) h3[o] = D1[o];
#pragma unroll
    for (int k = 0; k < 5; ++k)
#pragma unroll
        for (int o = 0; o < 5; ++o) h3[o] = fmaf(h2[k], C1[k * 5 + o], h3[o]);
#pragma unroll
    for (int o = 0; o < 5; ++o) h3[o] = leaky_f(h3[o]);
    float o0 = D2[0], o1 = D2[1];
#pragma unroll
    for (int k = 0; k < 5; ++k) {
        o0 = fmaf(h3[k], C2[k * 2 + 0], o0);
        o1 = fmaf(h3[k], C2[k * 2 + 1], o1);
    }
    out[(size_t)i * 2 + 0] = o0;
    out[(size_t)i * 2 + 1] = o1;
}

// ---------------------------------------------------------------------------

extern "C" void kernel_launch(void* const* d_in, const int* in_sizes, int n_in,
                              void* d_out, int out_size, void* d_ws, size_t ws_size,
                              hipStream_t stream)
{
    const float* x   = (const float*)d_in[0];
    const int*   ep  = (const int*)d_in[1];
    const int*   es  = (const int*)d_in[2];
    const int*   ev  = (const int*)d_in[3];
    const float* Wp  = (const float*)d_in[4];
    const float* bp  = (const float*)d_in[5];
    const float* Ws  = (const float*)d_in[6];
    const float* bs  = (const float*)d_in[7];
    const float* Wv  = (const float*)d_in[8];
    const float* bv  = (const float*)d_in[9];
    const float* pw1 = (const float*)d_in[10];
    const float* pb1 = (const float*)d_in[11];
    const float* pw2 = (const float*)d_in[12];
    const float* pb2 = (const float*)d_in[13];
    const float* cw1 = (const float*)d_in[14];
    const float* cb1 = (const float*)d_in[15];
    const float* cw2 = (const float*)d_in[16];
    const float* cb2 = (const float*)d_in[17];
    float* out = (float*)d_out;

    const size_t X4_BYTES    = 3ULL * N_NODES * sizeof(float4);  // 24 MB
    const size_t X12_BYTES   = 3ULL * N_NODES * sizeof(float2);  // 12 MB
    const size_t PARTS_BYTES = 3ULL * N_EDGES * sizeof(uint);    // 96 MB
    const size_t META_BYTES  = 9ULL * NBKT * sizeof(uint);
    const size_t NEED = X4_BYTES + X12_BYTES + PARTS_BYTES + META_BYTES + 256;

    if (ws_size >= NEED) {
        float4* X4    = (float4*)d_ws;
        float2* X12   = (float2*)((char*)d_ws + X4_BYTES);
        uint*  parts  = (uint*)((char*)d_ws + X4_BYTES + X12_BYTES);
        uint*  counts = parts + 3ULL * N_EDGES;
        uint*  basep  = counts + 3 * NBKT;
        uint*  cursor = basep + 3 * NBKT;

        int gridN = (N_NODES + 255) / 256;
        dim3 gridP1(P1_BLOCKS, 3);

        k0_zero<<<(3 * NBKT + 255) / 256, 256, 0, stream>>>(counts);
        k1_hx<<<gridN, 256, 0, stream>>>(x, Wp, Ws, Wv, X4, X12);
        p1_count<<<gridP1, P1_BLK, 0, stream>>>(ep, es, ev, counts);
        p1_scan<<<3, 1024, 0, stream>>>(counts, basep, cursor);
        p1_scatter<<<gridP1, P1_BLK, 0, stream>>>(ep, es, ev, cursor, parts);
        p2_prep<<<NBKT, 256, 0, stream>>>(parts, basep, counts, X4, X12);
        p2_agg<<<NBKT, 256, 0, stream>>>(parts, basep, counts, X4, X12,
                                         bp, bs, bv,
                                         pw1, pb1, pw2, pb2,
                                         cw1, cb1, cw2, cb2, out);
    } else {
        float* ws    = (float*)d_ws;
        float* h     = ws;
        float* deg   = h + 3L * N_NODES * 5;
        float* accum = deg + 3L * N_NODES;

        const int BLK = 256;
        int gridN = (N_NODES + BLK - 1) / BLK;
        long totalE = 3L * N_EDGES;
        int gridE = (int)((totalE + BLK - 1) / BLK);

        k1_gemm_deginit<<<gridN, BLK, 0, stream>>>(x, Wp, Ws, Wv, h, deg);
        k2_degree<<<gridE, BLK, 0, stream>>>(ep, es, ev, deg);
        k3_accum_init<<<gridN, BLK, 0, stream>>>(h, deg, bp, bs, bv, accum);
        k4_scatter<<<gridE, BLK, 0, stream>>>(ep, es, ev, h, deg, accum);
        k5_mlp<<<gridN, BLK, 0, stream>>>(accum, pw1, pb1, pw2, pb2, cw1, cb1, cw2, cb2, out);
    }
}

// Round 4
// 1173.693 us; speedup vs baseline: 1.1564x; 1.1564x over previous
//
#include <hip/hip_runtime.h>

#define N_NODES 500000
#define N_EDGES 8000000
#define W_BKT 512
#define LOG_W 9
#define NBKT ((N_NODES + W_BKT - 1) / W_BKT)   // 977
#define NPAD (NBKT * W_BKT)                    // 500224
#define EPAD (N_EDGES + 8 * NBKT)              // 8007816 (multiple of 8)
#define SRC_MASK 0x7FFFFu                      // 19 bits
#define P1_BLK 256
#define P1_EPT 64
#define P1_CHUNK (P1_BLK * P1_EPT)             // 16384 edges per block
#define P1_BLOCKS ((N_EDGES + P1_CHUNK - 1) / P1_CHUNK)  // 489

typedef unsigned int uint;

__device__ __forceinline__ float leaky_f(float x) { return x > 0.0f ? x : 0.1f * x; }

// ---------------------------------------------------------------------------
// FAST PATH
// ---------------------------------------------------------------------------

__global__ void k0_zero(uint* __restrict__ counts) {
    int t = blockIdx.x * blockDim.x + threadIdx.x;
    if (t < 3 * NBKT) counts[t] = 0;
}

// k1: H[s][i] = {h0..h4, 0, 0, 0}  (stride 8 floats = 32B record, single-line gather)
__global__ void k1_hx(const float* __restrict__ x,
                      const float* __restrict__ Wp,
                      const float* __restrict__ Ws,
                      const float* __restrict__ Wv,
                      float* __restrict__ H)
{
    __shared__ float sW[3][25][5];
    int t = threadIdx.x;
    if (t < 125) {
        sW[0][t / 5][t % 5] = Wp[t];
        sW[1][t / 5][t % 5] = Ws[t];
        sW[2][t / 5][t % 5] = Wv[t];
    }
    __syncthreads();
    int i = blockIdx.x * blockDim.x + t;
    if (i >= N_NODES) return;
    float xi[25];
#pragma unroll
    for (int k = 0; k < 25; ++k) xi[k] = x[i * 25 + k];
#pragma unroll
    for (int s = 0; s < 3; ++s) {
        float acc[5] = {0.f, 0.f, 0.f, 0.f, 0.f};
#pragma unroll
        for (int k = 0; k < 25; ++k)
#pragma unroll
            for (int c = 0; c < 5; ++c) acc[c] = fmaf(xi[k], sW[s][k][c], acc[c]);
        float* hp = H + ((size_t)s * N_NODES + i) * 8;
        *(float4*)hp = make_float4(acc[0], acc[1], acc[2], acc[3]);
        *(float4*)(hp + 4) = make_float4(acc[4], 0.f, 0.f, 0.f);
    }
}

// P1a: per-bucket edge counts; persist per-block hist rows for p1_scatter
__global__ void p1_count(const int* __restrict__ ep,
                         const int* __restrict__ es,
                         const int* __restrict__ ev,
                         uint* __restrict__ counts,
                         uint* __restrict__ bh)
{
    int s = blockIdx.y;
    const int* ei = (s == 0) ? ep : ((s == 1) ? es : ev);
    const uint4* d4 = (const uint4*)((const uint*)ei + N_EDGES);
    __shared__ uint hist[NBKT];
    for (int b = threadIdx.x; b < NBKT; b += P1_BLK) hist[b] = 0;
    __syncthreads();
    int base4 = blockIdx.x * (P1_CHUNK / 4);
#pragma unroll 4
    for (int j = 0; j < P1_EPT / 4; ++j) {
        int g4 = base4 + j * P1_BLK + threadIdx.x;
        if (g4 < N_EDGES / 4) {
            uint4 d = d4[g4];
            atomicAdd(&hist[d.x >> LOG_W], 1u);
            atomicAdd(&hist[d.y >> LOG_W], 1u);
            atomicAdd(&hist[d.z >> LOG_W], 1u);
            atomicAdd(&hist[d.w >> LOG_W], 1u);
        }
    }
    __syncthreads();
    uint* bhrow = bh + ((size_t)s * P1_BLOCKS + blockIdx.x) * NBKT;
    for (int b = threadIdx.x; b < NBKT; b += P1_BLK) {
        uint c = hist[b];
        bhrow[b] = c;
        if (c) atomicAdd(&counts[s * NBKT + b], c);
    }
}

// P1b: exclusive scan of 8-aligned-padded counts (bucket bases 32B-aligned)
__global__ void p1_scan(const uint* __restrict__ counts,
                        uint* __restrict__ base,
                        uint* __restrict__ cursor)
{
    __shared__ uint buf[1024];
    int s = blockIdx.x;
    int t = threadIdx.x;
    uint v = (t < NBKT) ? ((counts[s * NBKT + t] + 7u) & ~7u) : 0u;
    buf[t] = v;
    __syncthreads();
    for (int off = 1; off < 1024; off <<= 1) {
        uint add = (t >= off) ? buf[t - off] : 0u;
        __syncthreads();
        buf[t] += add;
        __syncthreads();
    }
    if (t < NBKT) {
        uint ex = buf[t] - v;
        base[s * NBKT + t] = ex;
        cursor[s * NBKT + t] = ex;
    }
}

// P1c: scatter edges into bucket-sorted parts, packed (local_dst<<19 | src).
// Uses persisted per-block hist (no re-histogram pass).
__global__ void p1_scatter(const int* __restrict__ ep,
                           const int* __restrict__ es,
                           const int* __restrict__ ev,
                           const uint* __restrict__ bh,
                           uint* __restrict__ cursor,
                           uint* __restrict__ parts)
{
    int s = blockIdx.y;
    const int* ei = (s == 0) ? ep : ((s == 1) ? es : ev);
    const uint4* s4 = (const uint4*)((const uint*)ei);
    const uint4* d4 = (const uint4*)((const uint*)ei + N_EDGES);
    uint* part = parts + (size_t)s * EPAD;
    __shared__ uint hist[NBKT];
    __shared__ uint bbase[NBKT];
    const uint* bhrow = bh + ((size_t)s * P1_BLOCKS + blockIdx.x) * NBKT;
    for (int b = threadIdx.x; b < NBKT; b += P1_BLK) {
        uint c = bhrow[b];
        bbase[b] = c ? atomicAdd(&cursor[s * NBKT + b], c) : 0u;
        hist[b] = 0;
    }
    __syncthreads();
    int base4 = blockIdx.x * (P1_CHUNK / 4);
#pragma unroll 4
    for (int j = 0; j < P1_EPT / 4; ++j) {
        int g4 = base4 + j * P1_BLK + threadIdx.x;
        if (g4 < N_EDGES / 4) {
            uint4 sv = s4[g4];
            uint4 dv = d4[g4];
            {
                uint b = dv.x >> LOG_W, r = atomicAdd(&hist[b], 1u);
                part[bbase[b] + r] = ((dv.x & (W_BKT - 1u)) << 19) | sv.x;
            }
            {
                uint b = dv.y >> LOG_W, r = atomicAdd(&hist[b], 1u);
                part[bbase[b] + r] = ((dv.y & (W_BKT - 1u)) << 19) | sv.y;
            }
            {
                uint b = dv.z >> LOG_W, r = atomicAdd(&hist[b], 1u);
                part[bbase[b] + r] = ((dv.z & (W_BKT - 1u)) << 19) | sv.z;
            }
            {
                uint b = dv.w >> LOG_W, r = atomicAdd(&hist[b], 1u);
                part[bbase[b] + r] = ((dv.w & (W_BKT - 1u)) << 19) | sv.w;
            }
        }
    }
}

// P2a: per-(set,bucket) degree hist -> premultiply H records by rd, store rd in slot 5
__global__ void p2a_deg(const uint* __restrict__ parts,
                        const uint* __restrict__ base,
                        const uint* __restrict__ counts,
                        float* __restrict__ H)
{
    int b = blockIdx.x, s = blockIdx.y;
    __shared__ uint cnt[W_BKT];
    for (int t = threadIdx.x; t < W_BKT; t += 256) cnt[t] = 0;
    __syncthreads();
    uint s0 = base[s * NBKT + b], c0 = counts[s * NBKT + b];
    const uint* pp = parts + (size_t)s * EPAD + s0;
    for (uint i = threadIdx.x; i < c0; i += 256) atomicAdd(&cnt[pp[i] >> 19], 1u);
    __syncthreads();
    int nb = b << LOG_W;
    float* Hs = H + (size_t)s * N_NODES * 8;
    for (int n = threadIdx.x; n < W_BKT; n += 256) {
        int node = nb + n;
        if (node < N_NODES) {
            float rd = rsqrtf(1.0f + (float)cnt[n]);
            float* hp = Hs + (size_t)node * 8;
            float4 v = *(float4*)hp;
            v.x *= rd; v.y *= rd; v.z *= rd; v.w *= rd;
            *(float4*)hp = v;
            float h4 = hp[4];
            *(float4*)(hp + 4) = make_float4(h4 * rd, rd, 0.f, 0.f);
        }
    }
}

// P2b: per-(set,bucket) aggregation in LDS, 8-edge ILP, write accum plane
__global__ __launch_bounds__(256, 4) void p2b_agg(
    const uint* __restrict__ parts, const uint* __restrict__ base,
    const uint* __restrict__ counts, const float* __restrict__ H,
    const float* __restrict__ bp, const float* __restrict__ bs, const float* __restrict__ bv,
    float* __restrict__ accum)
{
    __shared__ float acc[W_BKT * 5];   // 10 KB
    __shared__ float rdd[W_BKT];       // 2 KB
    __shared__ float sb[5];
    int b = blockIdx.x, s = blockIdx.y;
    int tid = threadIdx.x;
    const float* bbg = (s == 0) ? bp : ((s == 1) ? bs : bv);
    if (tid < 5) sb[tid] = bbg[tid];
    __syncthreads();
    int nb = b << LOG_W;
    const float* Hs = H + (size_t)s * N_NODES * 8;

    // self-loop + bias init: acc = h_pm * rd + bias  (= h_raw/deg + bias)
    for (int n = tid; n < W_BKT; n += 256) {
        int node = nb + n;
        float* a = &acc[n * 5];
        if (node < N_NODES) {
            const float* hp = Hs + (size_t)node * 8;
            float4 v = *(const float4*)hp;
            float h4 = hp[4];
            float rd = hp[5];
            rdd[n] = rd;
            a[0] = fmaf(v.x, rd, sb[0]);
            a[1] = fmaf(v.y, rd, sb[1]);
            a[2] = fmaf(v.z, rd, sb[2]);
            a[3] = fmaf(v.w, rd, sb[3]);
            a[4] = fmaf(h4, rd, sb[4]);
        } else {
            rdd[n] = 0.f;
#pragma unroll
            for (int c = 0; c < 5; ++c) a[c] = 0.f;
        }
    }
    __syncthreads();

    uint s0 = base[s * NBKT + b], c0 = counts[s * NBKT + b];
    const uint4* p4 = (const uint4*)(parts + (size_t)s * EPAD + s0);  // 32B-aligned
    uint niter = c0 / 2048u;
    for (uint it = 0; it < niter; ++it) {
        uint i4 = it * 512u + (uint)tid * 2u;
        uint4 ka = p4[i4];
        uint4 kb = p4[i4 + 1];
        uint k[8] = {ka.x, ka.y, ka.z, ka.w, kb.x, kb.y, kb.z, kb.w};
        float4 v[8];
        float  e[8];
        float  r[8];
        uint   ld[8];
#pragma unroll
        for (int j = 0; j < 8; ++j) {
            uint src = k[j] & SRC_MASK;
            ld[j] = k[j] >> 19;
            const float* hp = Hs + (size_t)src * 8;
            v[j] = *(const float4*)hp;     // 1 line miss
            e[j] = hp[4];                  // same line, L1 hit
            r[j] = rdd[ld[j]];
        }
#pragma unroll
        for (int j = 0; j < 8; ++j) {
            float* A = &acc[ld[j] * 5];
            atomicAdd(A + 0, v[j].x * r[j]);
            atomicAdd(A + 1, v[j].y * r[j]);
            atomicAdd(A + 2, v[j].z * r[j]);
            atomicAdd(A + 3, v[j].w * r[j]);
            atomicAdd(A + 4, e[j] * r[j]);
        }
    }
    const uint* pp = parts + (size_t)s * EPAD + s0;
    for (uint i = niter * 2048u + tid; i < c0; i += 256u) {
        uint kk = pp[i];
        uint src = kk & SRC_MASK;
        uint l = kk >> 19;
        const float* hp = Hs + (size_t)src * 8;
        float4 vv = *(const float4*)hp;
        float ee = hp[4];
        float rr = rdd[l];
        float* A = &acc[l * 5];
        atomicAdd(A + 0, vv.x * rr); atomicAdd(A + 1, vv.y * rr);
        atomicAdd(A + 2, vv.z * rr); atomicAdd(A + 3, vv.w * rr);
        atomicAdd(A + 4, ee * rr);
    }
    __syncthreads();

    float* op = accum + ((size_t)s * NPAD + nb) * 5;
    for (int t = tid; t < W_BKT * 5; t += 256) op[t] = acc[t];
}

// K6: per-node fused MLP epilogue
__global__ void k6_mlp(const float* __restrict__ accum,
                       const float* __restrict__ pw1, const float* __restrict__ pb1,
                       const float* __restrict__ pw2, const float* __restrict__ pb2,
                       const float* __restrict__ cw1, const float* __restrict__ cb1,
                       const float* __restrict__ cw2, const float* __restrict__ cb2,
                       float* __restrict__ out)
{
    __shared__ float sw[257];
    for (int j = threadIdx.x; j < 257; j += blockDim.x) {
        float v;
        if (j < 150) v = pw1[j];
        else if (j < 160) v = pb1[j - 150];
        else if (j < 210) v = pw2[j - 160];
        else if (j < 215) v = pb2[j - 210];
        else if (j < 240) v = cw1[j - 215];
        else if (j < 245) v = cb1[j - 240];
        else if (j < 255) v = cw2[j - 245];
        else v = cb2[j - 255];
        sw[j] = v;
    }
    __syncthreads();
    const float* W1 = sw;         // [15][10]
    const float* B1 = sw + 150;
    const float* W2 = sw + 160;   // [10][5]
    const float* B2 = sw + 210;
    const float* C1 = sw + 215;   // [5][5]
    const float* D1 = sw + 240;
    const float* C2 = sw + 245;   // [5][2]
    const float* D2 = sw + 255;

    int i = blockIdx.x * blockDim.x + threadIdx.x;
    if (i >= N_NODES) return;

    float hin[15];
#pragma unroll
    for (int s = 0; s < 3; ++s) {
        const float* ap = accum + ((size_t)s * NPAD + i) * 5;
#pragma unroll
        for (int c = 0; c < 5; ++c) hin[s * 5 + c] = leaky_f(ap[c]);
    }
    float h1[10];
#pragma unroll
    for (int o = 0; o < 10; ++o) h1[o] = B1[o];
#pragma unroll
    for (int k = 0; k < 15; ++k)
#pragma unroll
        for (int o = 0; o < 10; ++o) h1[o] = fmaf(hin[k], W1[k * 10 + o], h1[o]);
#pragma unroll
    for (int o = 0; o < 10; ++o) h1[o] = leaky_f(h1[o]);
    float h2[5];
#pragma unroll
    for (int o = 0; o < 5; ++o) h2[o] = B2[o];
#pragma unroll
    for (int k = 0; k < 10; ++k)
#pragma unroll
        for (int o = 0; o < 5; ++o) h2[o] = fmaf(h1[k], W2[k * 5 + o], h2[o]);
    float h3[5];
#pragma unroll
    for (int o = 0; o < 5; ++o) h3[o] = D1[o];
#pragma unroll
    for (int k = 0; k < 5; ++k)
#pragma unroll
        for (int o = 0; o < 5; ++o) h3[o] = fmaf(h2[k], C1[k * 5 + o], h3[o]);
#pragma unroll
    for (int o = 0; o < 5; ++o) h3[o] = leaky_f(h3[o]);
    float o0 = D2[0], o1 = D2[1];
#pragma unroll
    for (int k = 0; k < 5; ++k) {
        o0 = fmaf(h3[k], C2[k * 2 + 0], o0);
        o1 = fmaf(h3[k], C2[k * 2 + 1], o1);
    }
    out[(size_t)i * 2 + 0] = o0;
    out[(size_t)i * 2 + 1] = o1;
}

// ---------------------------------------------------------------------------
// FALLBACK PATH (round-0 pipeline, used only if ws too small)
// ---------------------------------------------------------------------------

__global__ void k1_gemm_deginit(const float* __restrict__ x,
                                const float* __restrict__ Wp,
                                const float* __restrict__ Ws,
                                const float* __restrict__ Wv,
                                float* __restrict__ h, float* __restrict__ deg)
{
    __shared__ float sW[3][25][5];
    int t = threadIdx.x;
    if (t < 125) { sW[0][t/5][t%5]=Wp[t]; sW[1][t/5][t%5]=Ws[t]; sW[2][t/5][t%5]=Wv[t]; }
    __syncthreads();
    for (int i = blockIdx.x * blockDim.x + t; i < N_NODES; i += gridDim.x * blockDim.x) {
        float xi[25];
#pragma unroll
        for (int k = 0; k < 25; ++k) xi[k] = x[i * 25 + k];
#pragma unroll
        for (int s = 0; s < 3; ++s) {
            float acc[5] = {0.f,0.f,0.f,0.f,0.f};
#pragma unroll
            for (int k = 0; k < 25; ++k)
#pragma unroll
                for (int c = 0; c < 5; ++c) acc[c] = fmaf(xi[k], sW[s][k][c], acc[c]);
#pragma unroll
            for (int c = 0; c < 5; ++c) h[(s * N_NODES + i) * 5 + c] = acc[c];
            deg[s * N_NODES + i] = 1.0f;
        }
    }
}

__global__ void k2_degree(const int* __restrict__ ep, const int* __restrict__ es,
                          const int* __restrict__ ev, float* __restrict__ deg)
{
    long e = (long)blockIdx.x * blockDim.x + threadIdx.x;
    if (e >= 3L * N_EDGES) return;
    int s = (int)(e / N_EDGES);
    int i = (int)(e - (long)s * N_EDGES);
    const int* ei = (s == 0) ? ep : ((s == 1) ? es : ev);
    atomicAdd(&deg[s * N_NODES + ei[N_EDGES + i]], 1.0f);
}

__global__ void k3_accum_init(const float* __restrict__ h, const float* __restrict__ deg,
                              const float* __restrict__ bp, const float* __restrict__ bs,
                              const float* __restrict__ bv, float* __restrict__ accum)
{
    int i = blockIdx.x * blockDim.x + threadIdx.x;
    if (i >= N_NODES) return;
#pragma unroll
    for (int s = 0; s < 3; ++s) {
        const float* b = (s == 0) ? bp : ((s == 1) ? bs : bv);
        float inv = 1.0f / deg[s * N_NODES + i];
#pragma unroll
        for (int c = 0; c < 5; ++c)
            accum[(s * N_NODES + i) * 5 + c] = h[(s * N_NODES + i) * 5 + c] * inv + b[c];
    }
}

__global__ void k4_scatter(const int* __restrict__ ep, const int* __restrict__ es,
                           const int* __restrict__ ev, const float* __restrict__ h,
                           const float* __restrict__ deg, float* __restrict__ accum)
{
    long e = (long)blockIdx.x * blockDim.x + threadIdx.x;
    if (e >= 3L * N_EDGES) return;
    int s = (int)(e / N_EDGES);
    int i = (int)(e - (long)s * N_EDGES);
    const int* ei = (s == 0) ? ep : ((s == 1) ? es : ev);
    int src = ei[i];
    int dst = ei[N_EDGES + i];
    float norm = rsqrtf(deg[s * N_NODES + src] * deg[s * N_NODES + dst]);
    const float* hp = h + (size_t)(s * N_NODES + src) * 5;
    float* ap = accum + (size_t)(s * N_NODES + dst) * 5;
#pragma unroll
    for (int c = 0; c < 5; ++c) atomicAdd(&ap[c], hp[c] * norm);
}

__global__ void k5_mlp(const float* __restrict__ accum,
                       const float* __restrict__ pw1, const float* __restrict__ pb1,
                       const float* __restrict__ pw2, const float* __restrict__ pb2,
                       const float* __restrict__ cw1, const float* __restrict__ cb1,
                       const float* __restrict__ cw2, const float* __restrict__ cb2,
                       float* __restrict__ out)
{
    __shared__ float sw[257];
    for (int j = threadIdx.x; j < 257; j += blockDim.x) {
        float v;
        if (j < 150) v = pw1[j];
        else if (j < 160) v = pb1[j - 150];
        else if (j < 210) v = pw2[j - 160];
        else if (j < 215) v = pb2[j - 210];
        else if (j < 240) v = cw1[j - 215];
        else if (j < 245) v = cb1[j - 240];
        else if (j < 255) v = cw2[j - 245];
        else v = cb2[j - 255];
        sw[j] = v;
    }
    __syncthreads();
    const float* W1 = sw; const float* B1 = sw + 150; const float* W2 = sw + 160;
    const float* B2 = sw + 210; const float* C1 = sw + 215; const float* D1 = sw + 240;
    const float* C2 = sw + 245; const float* D2 = sw + 255;
    int i = blockIdx.x * blockDim.x + threadIdx.x;
    if (i >= N_NODES) return;
    float hin[15];
#pragma unroll
    for (int s = 0; s < 3; ++s)
#pragma unroll
        for (int c = 0; c < 5; ++c)
            hin[s * 5 + c] = leaky_f(accum[(size_t)(s * N_NODES + i) * 5 + c]);
    float h1[10];
#pragma unroll
    for (int o = 0; o < 10; ++o) h1[o] = B1[o];
#pragma unroll
    for (int k = 0; k < 15; ++k)
#pragma unroll
        for (int o = 0; o < 10; ++o) h1[o] = fmaf(hin[k], W1[k * 10 + o], h1[o]);
#pragma unroll
    for (int o = 0; o < 10; ++o) h1[o] = leaky_f(h1[o]);
    float h2[5];
#pragma unroll
    for (int o = 0; o < 5; ++o) h2[o] = B2[o];
#pragma unroll
    for (int k = 0; k < 10; ++k)
#pragma unroll
        for (int o = 0; o < 5; ++o) h2[o] = fmaf(h1[k], W2[k * 5 + o], h2[o]);
    float h3[5];
#pragma unroll
    for (int o = 0; o < 5; ++o) h3[o] = D1[o];
#pragma unroll
    for (int k = 0; k < 5; ++k)
#pragma unroll
        for (int o = 0; o < 5; ++o) h3[o] = fmaf(h2[k], C1[k * 5 + o], h3[o]);
#pragma unroll
    for (int o = 0; o < 5; ++o) h3[o] = leaky_f(h3[o]);
    float o0 = D2[0], o1 = D2[1];
#pragma unroll
    for (int k = 0; k < 5; ++k) {
        o0 = fmaf(h3[k], C2[k * 2 + 0], o0);
        o1 = fmaf(h3[k], C2[k * 2 + 1], o1);
    }
    out[(size_t)i * 2 + 0] = o0;
    out[(size_t)i * 2 + 1] = o1;
}

// ---------------------------------------------------------------------------

extern "C" void kernel_launch(void* const* d_in, const int* in_sizes, int n_in,
                              void* d_out, int out_size, void* d_ws, size_t ws_size,
                              hipStream_t stream)
{
    const float* x   = (const float*)d_in[0];
    const int*   ep  = (const int*)d_in[1];
    const int*   es  = (const int*)d_in[2];
    const int*   ev  = (const int*)d_in[3];
    const float* Wp  = (const float*)d_in[4];
    const float* bp  = (const float*)d_in[5];
    const float* Ws  = (const float*)d_in[6];
    const float* bs  = (const float*)d_in[7];
    const float* Wv  = (const float*)d_in[8];
    const float* bv  = (const float*)d_in[9];
    const float* pw1 = (const float*)d_in[10];
    const float* pb1 = (const float*)d_in[11];
    const float* pw2 = (const float*)d_in[12];
    const float* pb2 = (const float*)d_in[13];
    const float* cw1 = (const float*)d_in[14];
    const float* cb1 = (const float*)d_in[15];
    const float* cw2 = (const float*)d_in[16];
    const float* cb2 = (const float*)d_in[17];
    float* out = (float*)d_out;

    const size_t H_BYTES     = 3ULL * N_NODES * 8 * 4;          // 48.0 MB
    const size_t ACC_BYTES   = 3ULL * NPAD * 5 * 4;             // 30.0 MB
    const size_t PARTS_BYTES = 3ULL * EPAD * 4;                 // 96.1 MB
    const size_t META_BYTES  = 9ULL * NBKT * 4;                 // counts/base/cursor
    const size_t BH_BYTES    = 3ULL * P1_BLOCKS * NBKT * 4;     // 5.7 MB
    const size_t NEED = H_BYTES + ACC_BYTES + PARTS_BYTES + META_BYTES + BH_BYTES + 256;

    if (ws_size >= NEED) {
        float* H      = (float*)d_ws;
        float* accum  = H + 3ULL * N_NODES * 8;
        uint*  parts  = (uint*)(accum + 3ULL * NPAD * 5);
        uint*  counts = parts + 3ULL * EPAD;
        uint*  basep  = counts + 3 * NBKT;
        uint*  cursor = basep + 3 * NBKT;
        uint*  bh     = cursor + 3 * NBKT;

        int gridN = (N_NODES + 255) / 256;
        dim3 gridP1(P1_BLOCKS, 3);
        dim3 gridP2(NBKT, 3);

        k0_zero<<<(3 * NBKT + 255) / 256, 256, 0, stream>>>(counts);
        k1_hx<<<gridN, 256, 0, stream>>>(x, Wp, Ws, Wv, H);
        p1_count<<<gridP1, P1_BLK, 0, stream>>>(ep, es, ev, counts, bh);
        p1_scan<<<3, 1024, 0, stream>>>(counts, basep, cursor);
        p1_scatter<<<gridP1, P1_BLK, 0, stream>>>(ep, es, ev, bh, cursor, parts);
        p2a_deg<<<gridP2, 256, 0, stream>>>(parts, basep, counts, H);
        p2b_agg<<<gridP2, 256, 0, stream>>>(parts, basep, counts, H,
                                            bp, bs, bv, accum);
        k6_mlp<<<gridN, 256, 0, stream>>>(accum, pw1, pb1, pw2, pb2,
                                          cw1, cb1, cw2, cb2, out);
    } else {
        float* ws    = (float*)d_ws;
        float* h     = ws;
        float* deg   = h + 3L * N_NODES * 5;
        float* accum = deg + 3L * N_NODES;

        const int BLK = 256;
        int gridN = (N_NODES + BLK - 1) / BLK;
        long totalE = 3L * N_EDGES;
        int gridE = (int)((totalE + BLK - 1) / BLK);

        k1_gemm_deginit<<<gridN, BLK, 0, stream>>>(x, Wp, Ws, Wv, h, deg);
        k2_degree<<<gridE, BLK, 0, stream>>>(ep, es, ev, deg);
        k3_accum_init<<<gridN, BLK, 0, stream>>>(h, deg, bp, bs, bv, accum);
        k4_scatter<<<gridE, BLK, 0, stream>>>(ep, es, ev, h, deg, accum);
        k5_mlp<<<gridN, BLK, 0, stream>>>(accum, pw1, pb1, pw2, pb2, cw1, cb1, cw2, cb2, out);
    }
}